// Round 2
// baseline (460.522 us; speedup 1.0000x reference)
//
#include <hip/hip_runtime.h>
#include <math.h>

// Problem constants (B=2, C=64, inter=32, H=W=80 -> N=6400)
#define BATCH 2
#define CH    64
#define INTER 32
#define NPOS  6400

// ---------------------------------------------------------------------------
// Kernel 1: QKV projections.  Q=theta_w@x, K=phi_w@x, V=g_w@x, each [B][N][32]
// stored fp32 in workspace.  x is [B][C][N] fp32.
// Grid: (N/64, B), 256 threads.
// ---------------------------------------------------------------------------
__global__ __launch_bounds__(256) void nlb_proj_kernel(
    const float* __restrict__ x,
    const float* __restrict__ g_w,
    const float* __restrict__ th_w,
    const float* __restrict__ ph_w,
    float* __restrict__ Q, float* __restrict__ K, float* __restrict__ V)
{
    __shared__ float w[96][64];   // rows 0-31 theta, 32-63 phi, 64-95 g
    __shared__ float xs[64][64];  // [c][pos]
    const int b  = blockIdx.y;
    const int n0 = blockIdx.x * 64;
    const int t  = threadIdx.x;

    for (int idx = t; idx < 2048; idx += 256) {
        int r = idx >> 6, c = idx & 63;
        w[r][c]      = th_w[idx];
        w[32 + r][c] = ph_w[idx];
        w[64 + r][c] = g_w[idx];
    }
    const float* xb = x + (size_t)b * CH * NPOS + n0;
    for (int idx = t; idx < 4096; idx += 256) {
        int c = idx >> 6, j = idx & 63;
        xs[c][j] = xb[(size_t)c * NPOS + j];
    }
    __syncthreads();

    // 96 rows x 64 positions = 6144 outputs; 24 per thread.
    for (int o = 0; o < 24; o++) {
        int idx = t + o * 256;
        int row = idx >> 6, j = idx & 63;
        float acc = 0.f;
        #pragma unroll
        for (int c = 0; c < 64; c++) acc += w[row][c] * xs[c][j];
        int p = row >> 5, i = row & 31;
        float* dst = (p == 0) ? Q : (p == 1) ? K : V;
        dst[((size_t)b * NPOS + n0 + j) * INTER + i] = acc;
    }
}

// ---------------------------------------------------------------------------
// Kernel 2: flash attention (no scale) + output projection + residual.
// Grid: (N/16, B), 256 threads.  Each block: 16 query rows; 16 lanes per row.
// K/V staged in LDS transposed [dim][key] with rows padded to 68 floats
// (272 B = 17*16 -> float4-aligned; all LDS arrays are 16B-multiple sized so
// every row base stays 16B-aligned regardless of packing order).
// ---------------------------------------------------------------------------
__global__ __launch_bounds__(256) void nlb_flash_kernel(
    const float* __restrict__ Q, const float* __restrict__ K,
    const float* __restrict__ V,
    const float* __restrict__ x,
    const float* __restrict__ w_w,   // [64][32]
    float* __restrict__ out)
{
    const int b  = blockIdx.y;
    const int m0 = blockIdx.x * 16;
    const int t  = threadIdx.x;
    const int r  = t >> 4;    // query row within tile (0..15)
    const int s  = t & 15;    // lane within row

    __shared__ __align__(16) float ks[32][68];
    __shared__ __align__(16) float vs[32][68];
    __shared__ __align__(16) float qs[16][32];
    __shared__ __align__(16) float wf[64][32];
    __shared__ __align__(16) float of[16][32];

    for (int idx = t; idx < 2048; idx += 256)
        wf[idx >> 5][idx & 31] = w_w[idx];
    {   // 512 Q elements, 2 per thread
        int idx = t * 2;
        const float* qg = Q + ((size_t)b * NPOS + m0) * INTER;
        int row = idx >> 5, i = idx & 31;
        qs[row][i]     = qg[idx];
        qs[row][i + 1] = qg[idx + 1];
    }
    __syncthreads();

    float qreg[32];
    #pragma unroll
    for (int c = 0; c < 32; c++) qreg[c] = qs[r][c];

    float run_m = -1e30f, run_l = 0.f;
    float o_acc[32];
    #pragma unroll
    for (int c = 0; c < 32; c++) o_acc[c] = 0.f;

    const float* Kb = K + (size_t)b * NPOS * INTER;
    const float* Vb = V + (size_t)b * NPOS * INTER;

    for (int kt = 0; kt < NPOS / 64; kt++) {
        __syncthreads();  // previous iter's LDS reads done before overwrite
        const float* kg = Kb + (size_t)kt * 64 * INTER;
        const float* vg = Vb + (size_t)kt * 64 * INTER;
        for (int idx = t; idx < 2048; idx += 256) {
            int j = idx >> 5, i = idx & 31;     // key j, dim i
            ks[i][j] = kg[idx];
            vs[i][j] = vg[idx];
        }
        __syncthreads();

        // scores for this thread's 4 contiguous keys: 4s..4s+3
        float sc0 = 0.f, sc1 = 0.f, sc2 = 0.f, sc3 = 0.f;
        #pragma unroll
        for (int c = 0; c < 32; c++) {
            const float4 kv = *(const float4*)&ks[c][4 * s];
            float qv = qreg[c];
            sc0 += qv * kv.x; sc1 += qv * kv.y;
            sc2 += qv * kv.z; sc3 += qv * kv.w;
        }
        float mloc = fmaxf(fmaxf(sc0, sc1), fmaxf(sc2, sc3));
        #pragma unroll
        for (int mask = 1; mask < 16; mask <<= 1)
            mloc = fmaxf(mloc, __shfl_xor(mloc, mask));
        float new_m = fmaxf(run_m, mloc);
        float alpha = __expf(run_m - new_m);
        float p0 = __expf(sc0 - new_m), p1 = __expf(sc1 - new_m);
        float p2 = __expf(sc2 - new_m), p3 = __expf(sc3 - new_m);
        float lloc = p0 + p1 + p2 + p3;
        #pragma unroll
        for (int mask = 1; mask < 16; mask <<= 1)
            lloc += __shfl_xor(lloc, mask);
        run_l = run_l * alpha + lloc;
        run_m = new_m;
        #pragma unroll
        for (int c = 0; c < 32; c++) {
            const float4 vv = *(const float4*)&vs[c][4 * s];
            o_acc[c] = o_acc[c] * alpha + p0 * vv.x + p1 * vv.y + p2 * vv.z + p3 * vv.w;
        }
    }

    // reduce partial O across the 16 lanes of each row (butterfly -> all lanes
    // hold the total); lane 0 of each row writes with STATIC indices.
    #pragma unroll
    for (int c = 0; c < 32; c++) {
        float v = o_acc[c];
        v += __shfl_xor(v, 1); v += __shfl_xor(v, 2);
        v += __shfl_xor(v, 4); v += __shfl_xor(v, 8);
        o_acc[c] = v;
    }
    float inv_l = 1.f / run_l;
    if (s == 0) {
        #pragma unroll
        for (int c = 0; c < 32; c++) of[r][c] = o_acc[c] * inv_l;
    }
    __syncthreads();

    // output projection + residual: thread handles row r, channels s+16k
    const float* xb = x   + (size_t)b * CH * NPOS;
    float*       ob = out + (size_t)b * CH * NPOS;
    #pragma unroll
    for (int k = 0; k < 4; k++) {
        int cc = s + k * 16;
        float acc = 0.f;
        #pragma unroll
        for (int i = 0; i < 32; i++) acc += wf[cc][i] * of[r][i];
        size_t off = (size_t)cc * NPOS + m0 + r;
        ob[off] = acc + xb[off];
    }
}

extern "C" void kernel_launch(void* const* d_in, const int* in_sizes, int n_in,
                              void* d_out, int out_size, void* d_ws, size_t ws_size,
                              hipStream_t stream) {
    const float* x    = (const float*)d_in[0];
    const float* g_w  = (const float*)d_in[1];
    const float* th_w = (const float*)d_in[2];
    const float* ph_w = (const float*)d_in[3];
    const float* w_w  = (const float*)d_in[4];
    float* out = (float*)d_out;

    float* Q = (float*)d_ws;                       // [B][N][32]
    float* K = Q + (size_t)BATCH * NPOS * INTER;   // [B][N][32]
    float* V = K + (size_t)BATCH * NPOS * INTER;   // [B][N][32]

    nlb_proj_kernel<<<dim3(NPOS / 64, BATCH), 256, 0, stream>>>(
        x, g_w, th_w, ph_w, Q, K, V);
    nlb_flash_kernel<<<dim3(NPOS / 16, BATCH), 256, 0, stream>>>(
        Q, K, V, x, w_w, out);
}

// Round 3
// 234.961 us; speedup vs baseline: 1.9600x; 1.9600x over previous
//
#include <hip/hip_runtime.h>
#include <hip/hip_bf16.h>
#include <math.h>

// Problem constants (B=2, C=64, inter=32, H=W=80 -> N=6400)
#define BATCH 2
#define CH    64
#define INTER 32
#define NPOS  6400
#define LOG2E 1.44269504088896f

typedef __attribute__((ext_vector_type(8))) short bf16x8;  // 8 bf16 (4 VGPRs)
typedef __attribute__((ext_vector_type(4))) float f32x4;   // MFMA C/D

static __device__ __forceinline__ short f2bf(float f) {
    __hip_bfloat16 h = __float2bfloat16(f);  // RNE
    return *reinterpret_cast<short*>(&h);
}
static __device__ __forceinline__ float bf2f(short s) {
    __hip_bfloat16 h = *reinterpret_cast<__hip_bfloat16*>(&s);
    return __bfloat162float(h);
}

// ---------------------------------------------------------------------------
// Kernel 1: projections -> bf16 workspace.
//   Qhi/Qlo [b][n][32] : theta * log2(e), hi/lo split
//   Khi/Klo [b][n][32] : phi, hi/lo split
//   Vt      [b][32][n] : g, transposed (dim-major)
//   Wb      [64][32]   : w_w in bf16 (written by block (0,0))
// Grid: (N/64, B), 256 threads.
// ---------------------------------------------------------------------------
__global__ __launch_bounds__(256) void nlb_proj_kernel(
    const float* __restrict__ x,
    const float* __restrict__ g_w,
    const float* __restrict__ th_w,
    const float* __restrict__ ph_w,
    const float* __restrict__ w_w,
    short* __restrict__ Qhi, short* __restrict__ Qlo,
    short* __restrict__ Khi, short* __restrict__ Klo,
    short* __restrict__ Vt,  short* __restrict__ Wb)
{
    __shared__ float w[96][65];   // +1 pad: conflict-free column reads
    __shared__ float xs[64][64];
    const int b  = blockIdx.y;
    const int n0 = blockIdx.x * 64;
    const int t  = threadIdx.x;

    for (int idx = t; idx < 2048; idx += 256) {
        int r = idx >> 6, c = idx & 63;
        w[r][c]      = th_w[idx];
        w[32 + r][c] = ph_w[idx];
        w[64 + r][c] = g_w[idx];
    }
    const float* xb = x + (size_t)b * CH * NPOS + n0;
    for (int idx = t; idx < 4096; idx += 256) {
        int c = idx >> 6, j = idx & 63;
        xs[c][j] = xb[(size_t)c * NPOS + j];
    }
    __syncthreads();

    // 6144 outputs: idx -> (p = projection, i = inter-ch, j = position)
    for (int o = 0; o < 24; o++) {
        int idx = t + o * 256;
        int i = idx & 31, j = (idx >> 5) & 63, p = idx >> 11;
        float acc = 0.f;
        #pragma unroll
        for (int c = 0; c < 64; c++) acc += w[p * 32 + i][c] * xs[c][j];
        int n = n0 + j;
        if (p == 0) {                       // theta -> Q (log2-domain)
            float q = acc * LOG2E;
            short hi = f2bf(q);
            size_t off = ((size_t)b * NPOS + n) * 32 + i;
            Qhi[off] = hi;
            Qlo[off] = f2bf(q - bf2f(hi));
        } else if (p == 1) {                // phi -> K
            short hi = f2bf(acc);
            size_t off = ((size_t)b * NPOS + n) * 32 + i;
            Khi[off] = hi;
            Klo[off] = f2bf(acc - bf2f(hi));
        } else {                            // g -> V^T
            Vt[((size_t)b * 32 + i) * NPOS + n] = f2bf(acc);
        }
    }
    if (blockIdx.x == 0 && b == 0)
        for (int idx = t; idx < 2048; idx += 256) Wb[idx] = f2bf(w_w[idx]);
}

// ---------------------------------------------------------------------------
// Kernel 2: MFMA flash attention + W-projection + residual.
// Grid: (N/64, B), 256 threads = 4 waves, 16 queries/wave, 128-key tiles.
// Layouts (guide-verified): C/D col=lane&15,row=quad*4+reg;
//                           A[m=lane&15][k=quad*8+j]; B[k=quad*8+j][n=lane&15].
// ---------------------------------------------------------------------------
__global__ __launch_bounds__(256) void nlb_flash_kernel(
    const short* __restrict__ Qhi, const short* __restrict__ Qlo,
    const short* __restrict__ Khi, const short* __restrict__ Klo,
    const short* __restrict__ Vt,  const short* __restrict__ Wb,
    const float* __restrict__ x, float* __restrict__ out)
{
    // padded rows: khi/klo 40 shorts (80B, bank-quad stride 5 mod 8 -> even);
    // vt/pm 136 shorts (272B); ot 40 shorts (80B).
    __shared__ __align__(16) short khi_s[128][40];
    __shared__ __align__(16) short klo_s[128][40];
    __shared__ __align__(16) short vt_s[32][136];
    __shared__ __align__(16) short pm[4][16][136];   // per-wave P [query][key]
    __shared__ __align__(16) short ot[4][16][40];    // per-wave O [query][dim]

    const int b    = blockIdx.y;
    const int t    = threadIdx.x;
    const int w    = t >> 6;
    const int lane = t & 63;
    const int n16  = lane & 15;
    const int quad = lane >> 4;
    const int q0   = blockIdx.x * 64 + w * 16;   // wave's first query

    // Q fragments (A-layout), loaded once
    const size_t qoff = ((size_t)b * NPOS + q0 + n16) * 32 + quad * 8;
    const bf16x8 qhi = *(const bf16x8*)(Qhi + qoff);
    const bf16x8 qlo = *(const bf16x8*)(Qlo + qoff);

    f32x4 o0 = {0.f, 0.f, 0.f, 0.f};   // dims 0-15  (C-layout)
    f32x4 o1 = {0.f, 0.f, 0.f, 0.f};   // dims 16-31
    float runm[4] = {-1e30f, -1e30f, -1e30f, -1e30f};
    float runl[4] = {0.f, 0.f, 0.f, 0.f};

    const short* KhiB = Khi + (size_t)b * NPOS * 32;
    const short* KloB = Klo + (size_t)b * NPOS * 32;
    const short* VtB  = Vt  + (size_t)b * 32 * NPOS;

    for (int kt = 0; kt < NPOS / 128; kt++) {
        __syncthreads();   // previous tile's LDS reads complete
        {
            const int k0 = kt * 128;
            #pragma unroll
            for (int i = 0; i < 2; i++) {
                int c = t + i * 256;               // 512 x 16B chunks each
                int key = c >> 2, part = c & 3;
                bf16x8 ah = *(const bf16x8*)(KhiB + (size_t)(k0 + key) * 32 + part * 8);
                bf16x8 al2 = *(const bf16x8*)(KloB + (size_t)(k0 + key) * 32 + part * 8);
                *(bf16x8*)&khi_s[key][part * 8] = ah;
                *(bf16x8*)&klo_s[key][part * 8] = al2;
                int dim = c >> 4, kp = c & 15;
                bf16x8 vv = *(const bf16x8*)(VtB + (size_t)dim * NPOS + k0 + kp * 8);
                *(bf16x8*)&vt_s[dim][kp * 8] = vv;
            }
        }
        __syncthreads();

        // S = Q K^T, hi/lo split (3 MFMAs per 16-key group), log2-domain
        f32x4 sc[8];
        #pragma unroll
        for (int g = 0; g < 8; g++) {
            bf16x8 kh = *(const bf16x8*)&khi_s[g * 16 + n16][quad * 8];
            bf16x8 kl = *(const bf16x8*)&klo_s[g * 16 + n16][quad * 8];
            f32x4 z = {0.f, 0.f, 0.f, 0.f};
            z = __builtin_amdgcn_mfma_f32_16x16x32_bf16(qhi, kh, z, 0, 0, 0);
            z = __builtin_amdgcn_mfma_f32_16x16x32_bf16(qlo, kh, z, 0, 0, 0);
            z = __builtin_amdgcn_mfma_f32_16x16x32_bf16(qhi, kl, z, 0, 0, 0);
            sc[g] = z;
        }

        // online softmax over 128 keys (rows = quad*4+r, cols spread 16 lanes)
        #pragma unroll
        for (int r = 0; r < 4; r++) {
            float m = sc[0][r];
            #pragma unroll
            for (int g = 1; g < 8; g++) m = fmaxf(m, sc[g][r]);
            m = fmaxf(m, __shfl_xor(m, 1));
            m = fmaxf(m, __shfl_xor(m, 2));
            m = fmaxf(m, __shfl_xor(m, 4));
            m = fmaxf(m, __shfl_xor(m, 8));
            float nm = fmaxf(runm[r], m);
            float a  = __builtin_amdgcn_exp2f(runm[r] - nm);
            float l  = 0.f;
            #pragma unroll
            for (int g = 0; g < 8; g++) {
                float p = __builtin_amdgcn_exp2f(sc[g][r] - nm);
                sc[g][r] = p;
                l += p;
            }
            l += __shfl_xor(l, 1); l += __shfl_xor(l, 2);
            l += __shfl_xor(l, 4); l += __shfl_xor(l, 8);
            runl[r] = runl[r] * a + l;
            runm[r] = nm;
            o0[r] *= a; o1[r] *= a;
        }

        // P: C-layout -> per-wave LDS [query][key] (A-readable)
        #pragma unroll
        for (int g = 0; g < 8; g++) {
            #pragma unroll
            for (int r = 0; r < 4; r++)
                pm[w][quad * 4 + r][g * 16 + n16] = f2bf(sc[g][r]);
        }

        // O += P V  (4 K-chunks of 32 keys, 2 dim-halves)
        #pragma unroll
        for (int kc = 0; kc < 4; kc++) {
            bf16x8 pa = *(const bf16x8*)&pm[w][n16][kc * 32 + quad * 8];
            bf16x8 v0 = *(const bf16x8*)&vt_s[n16][kc * 32 + quad * 8];
            bf16x8 v1 = *(const bf16x8*)&vt_s[16 + n16][kc * 32 + quad * 8];
            o0 = __builtin_amdgcn_mfma_f32_16x16x32_bf16(pa, v0, o0, 0, 0, 0);
            o1 = __builtin_amdgcn_mfma_f32_16x16x32_bf16(pa, v1, o1, 0, 0, 0);
        }
    }

    // normalize, transpose O to [query][dim] bf16 (per-wave region)
    #pragma unroll
    for (int r = 0; r < 4; r++) {
        float inv = 1.f / runl[r];
        ot[w][quad * 4 + r][n16]      = f2bf(o0[r] * inv);
        ot[w][quad * 4 + r][16 + n16] = f2bf(o1[r] * inv);
    }

    // y = W o  (A = W 16ch x 32d, B = o^T 32d x 16q), + residual, store
    const float* xB   = x   + (size_t)b * CH * NPOS;
    float*       outB = out + (size_t)b * CH * NPOS;
    bf16x8 ofr = *(const bf16x8*)&ot[w][n16][quad * 8];
    #pragma unroll
    for (int cg = 0; cg < 4; cg++) {
        bf16x8 wfr = *(const bf16x8*)(Wb + (cg * 16 + n16) * 32 + quad * 8);
        f32x4 d = {0.f, 0.f, 0.f, 0.f};
        d = __builtin_amdgcn_mfma_f32_16x16x32_bf16(wfr, ofr, d, 0, 0, 0);
        #pragma unroll
        for (int r = 0; r < 4; r++) {
            int ch = cg * 16 + quad * 4 + r;
            size_t off = (size_t)ch * NPOS + q0 + n16;
            outB[off] = d[r] + xB[off];
        }
    }
}

extern "C" void kernel_launch(void* const* d_in, const int* in_sizes, int n_in,
                              void* d_out, int out_size, void* d_ws, size_t ws_size,
                              hipStream_t stream) {
    const float* x    = (const float*)d_in[0];
    const float* g_w  = (const float*)d_in[1];
    const float* th_w = (const float*)d_in[2];
    const float* ph_w = (const float*)d_in[3];
    const float* w_w  = (const float*)d_in[4];
    float* out = (float*)d_out;

    const size_t SZ = (size_t)BATCH * NPOS * INTER;  // 409600 shorts
    short* Qhi = (short*)d_ws;
    short* Qlo = Qhi + SZ;
    short* Khi = Qlo + SZ;
    short* Klo = Khi + SZ;
    short* Vt  = Klo + SZ;
    short* Wb  = Vt  + SZ;

    nlb_proj_kernel<<<dim3(NPOS / 64, BATCH), 256, 0, stream>>>(
        x, g_w, th_w, ph_w, w_w, Qhi, Qlo, Khi, Klo, Vt, Wb);
    nlb_flash_kernel<<<dim3(NPOS / 64, BATCH), 256, 0, stream>>>(
        Qhi, Qlo, Khi, Klo, Vt, Wb, x, out);
}

// Round 4
// 141.162 us; speedup vs baseline: 3.2624x; 1.6645x over previous
//
#include <hip/hip_runtime.h>
#include <hip/hip_bf16.h>
#include <math.h>

// Problem constants (B=2, C=64, inter=32, H=W=80 -> N=6400)
#define BATCH 2
#define CH    64
#define INTER 32
#define NPOS  6400
#define LOG2E 1.44269504088896f
#define SPLIT 10          // key-dim split factor
#define TPB   5           // 128-key tiles per split chunk (5*128*10 = 6400)

typedef __attribute__((ext_vector_type(8))) short bf16x8;  // 8 bf16 (4 VGPRs)
typedef __attribute__((ext_vector_type(4))) float f32x4;   // MFMA C/D
typedef _Float16 h4 __attribute__((ext_vector_type(4)));

static __device__ __forceinline__ short f2bf(float f) {
    __hip_bfloat16 h = __float2bfloat16(f);  // RNE
    return *reinterpret_cast<short*>(&h);
}
static __device__ __forceinline__ float bf2f(short s) {
    __hip_bfloat16 h = *reinterpret_cast<__hip_bfloat16*>(&s);
    return __bfloat162float(h);
}

// ---------------------------------------------------------------------------
// Kernel 1: projections. Grid (N/64, 3, B); blockIdx.y = projection
// (0=theta->Q log2-domain hi/lo, 1=phi->K hi/lo, 2=g->V^T).
// x tile lives in 64 VGPRs (coalesced loads, lane=position); W rows are
// wave-uniform -> scalar loads. LDS used only for the Q/K output transpose.
// ---------------------------------------------------------------------------
__global__ __launch_bounds__(256) void nlb_proj_kernel(
    const float* __restrict__ x,
    const float* __restrict__ g_w,
    const float* __restrict__ th_w,
    const float* __restrict__ ph_w,
    short* __restrict__ Qhi, short* __restrict__ Qlo,
    short* __restrict__ Khi, short* __restrict__ Klo,
    short* __restrict__ Vt)
{
    const int b  = blockIdx.z;
    const int p  = blockIdx.y;
    const int n0 = blockIdx.x * 64;
    const int t  = threadIdx.x;
    const int w  = __builtin_amdgcn_readfirstlane(t) >> 6;  // wave id (uniform)
    const int lane = t & 63;

    const float* wsrc = (p == 0) ? th_w : (p == 1) ? ph_w : g_w;
    const float* xg = x + (size_t)b * CH * NPOS + n0 + lane;

    float xr[64];
    #pragma unroll
    for (int c = 0; c < 64; c++) xr[c] = xg[(size_t)c * NPOS];

    __shared__ float buf[32][65];

    float accs[8];
    #pragma unroll
    for (int rr = 0; rr < 8; rr++) {
        const int row = w * 8 + rr;                  // wave-uniform
        const float* wr = wsrc + row * 64;           // -> scalar loads
        float a0 = 0.f, a1 = 0.f, a2 = 0.f, a3 = 0.f;
        #pragma unroll
        for (int c = 0; c < 16; c++) {
            a0 += wr[c]      * xr[c];
            a1 += wr[c + 16] * xr[c + 16];
            a2 += wr[c + 32] * xr[c + 32];
            a3 += wr[c + 48] * xr[c + 48];
        }
        accs[rr] = (a0 + a1) + (a2 + a3);
    }

    if (p == 2) {   // V^T: [b][32][N], lane-contiguous stores, no transpose
        #pragma unroll
        for (int rr = 0; rr < 8; rr++)
            Vt[((size_t)b * 32 + w * 8 + rr) * NPOS + n0 + lane] = f2bf(accs[rr]);
        return;
    }

    #pragma unroll
    for (int rr = 0; rr < 8; rr++) buf[w * 8 + rr][lane] = accs[rr];
    __syncthreads();

    const float scale = (p == 0) ? LOG2E : 1.f;
    short* dhi = (p == 0) ? Qhi : Khi;
    short* dlo = (p == 0) ? Qlo : Klo;
    const int pos = t >> 2, ic = t & 3;   // 8 consecutive inter-ch per thread
    bf16x8 hv, lv;
    #pragma unroll
    for (int j = 0; j < 8; j++) {
        float v = buf[ic * 8 + j][pos] * scale;
        short h = f2bf(v);
        hv[j] = h;
        lv[j] = f2bf(v - bf2f(h));
    }
    size_t off = ((size_t)b * NPOS + n0 + pos) * 32 + ic * 8;
    *(bf16x8*)(dhi + off) = hv;
    *(bf16x8*)(dlo + off) = lv;
}

// ---------------------------------------------------------------------------
// Kernel 2: MFMA flash attention, split-K. Grid (N/64, SPLIT, B), 4 waves.
// Each block: 64 queries vs 640 keys (5 tiles of 128). Writes per-split
// normalized partial O (fp16) and (m, l) (float2) to workspace.
// ---------------------------------------------------------------------------
__global__ __launch_bounds__(256) void nlb_flash_kernel(
    const short* __restrict__ Qhi, const short* __restrict__ Qlo,
    const short* __restrict__ Khi, const short* __restrict__ Klo,
    const short* __restrict__ Vt,
    _Float16* __restrict__ Opart, float2* __restrict__ ml)
{
    __shared__ __align__(16) short khi_s[128][40];
    __shared__ __align__(16) short klo_s[128][40];
    __shared__ __align__(16) short vt_s[32][136];
    __shared__ __align__(16) short pm[4][16][136];   // per-wave P [query][key]

    const int b     = blockIdx.z;
    const int split = blockIdx.y;
    const int t     = threadIdx.x;
    const int w     = t >> 6;
    const int lane  = t & 63;
    const int n16   = lane & 15;
    const int quad  = lane >> 4;
    const int q0    = blockIdx.x * 64 + w * 16;

    const size_t qoff = ((size_t)b * NPOS + q0 + n16) * 32 + quad * 8;
    const bf16x8 qhi = *(const bf16x8*)(Qhi + qoff);
    const bf16x8 qlo = *(const bf16x8*)(Qlo + qoff);

    f32x4 o0 = {0.f, 0.f, 0.f, 0.f};
    f32x4 o1 = {0.f, 0.f, 0.f, 0.f};
    float runm[4] = {-1e30f, -1e30f, -1e30f, -1e30f};
    float runl[4] = {0.f, 0.f, 0.f, 0.f};

    const short* KhiB = Khi + (size_t)b * NPOS * 32;
    const short* KloB = Klo + (size_t)b * NPOS * 32;
    const short* VtB  = Vt  + (size_t)b * 32 * NPOS;

    const int kt0 = split * TPB;
    for (int kt = kt0; kt < kt0 + TPB; kt++) {
        __syncthreads();
        {
            const int k0 = kt * 128;
            #pragma unroll
            for (int i = 0; i < 2; i++) {
                int c = t + i * 256;
                int key = c >> 2, part = c & 3;
                bf16x8 ah  = *(const bf16x8*)(KhiB + (size_t)(k0 + key) * 32 + part * 8);
                bf16x8 al2 = *(const bf16x8*)(KloB + (size_t)(k0 + key) * 32 + part * 8);
                *(bf16x8*)&khi_s[key][part * 8] = ah;
                *(bf16x8*)&klo_s[key][part * 8] = al2;
                int dim = c >> 4, kp = c & 15;
                bf16x8 vv = *(const bf16x8*)(VtB + (size_t)dim * NPOS + k0 + kp * 8);
                *(bf16x8*)&vt_s[dim][kp * 8] = vv;
            }
        }
        __syncthreads();

        // S = Q K^T (hi/lo split), log2-domain
        f32x4 sc[8];
        #pragma unroll
        for (int g = 0; g < 8; g++) {
            bf16x8 kh = *(const bf16x8*)&khi_s[g * 16 + n16][quad * 8];
            bf16x8 kl = *(const bf16x8*)&klo_s[g * 16 + n16][quad * 8];
            f32x4 z = {0.f, 0.f, 0.f, 0.f};
            z = __builtin_amdgcn_mfma_f32_16x16x32_bf16(qhi, kh, z, 0, 0, 0);
            z = __builtin_amdgcn_mfma_f32_16x16x32_bf16(qlo, kh, z, 0, 0, 0);
            z = __builtin_amdgcn_mfma_f32_16x16x32_bf16(qhi, kl, z, 0, 0, 0);
            sc[g] = z;
        }

        // online softmax (per row r; cols spread across 16 lanes)
        #pragma unroll
        for (int r = 0; r < 4; r++) {
            float m = sc[0][r];
            #pragma unroll
            for (int g = 1; g < 8; g++) m = fmaxf(m, sc[g][r]);
            m = fmaxf(m, __shfl_xor(m, 1));
            m = fmaxf(m, __shfl_xor(m, 2));
            m = fmaxf(m, __shfl_xor(m, 4));
            m = fmaxf(m, __shfl_xor(m, 8));
            float nm = fmaxf(runm[r], m);
            float a  = __builtin_amdgcn_exp2f(runm[r] - nm);
            float l  = 0.f;
            #pragma unroll
            for (int g = 0; g < 8; g++) {
                float p = __builtin_amdgcn_exp2f(sc[g][r] - nm);
                sc[g][r] = p;
                l += p;
            }
            l += __shfl_xor(l, 1); l += __shfl_xor(l, 2);
            l += __shfl_xor(l, 4); l += __shfl_xor(l, 8);
            runl[r] = runl[r] * a + l;
            runm[r] = nm;
            o0[r] *= a; o1[r] *= a;
        }

        // P: C-layout -> per-wave LDS (A-readable)
        #pragma unroll
        for (int g = 0; g < 8; g++) {
            #pragma unroll
            for (int r = 0; r < 4; r++)
                pm[w][quad * 4 + r][g * 16 + n16] = f2bf(sc[g][r]);
        }

        // O += P V
        #pragma unroll
        for (int kc = 0; kc < 4; kc++) {
            bf16x8 pa = *(const bf16x8*)&pm[w][n16][kc * 32 + quad * 8];
            bf16x8 v0 = *(const bf16x8*)&vt_s[n16][kc * 32 + quad * 8];
            bf16x8 v1 = *(const bf16x8*)&vt_s[16 + n16][kc * 32 + quad * 8];
            o0 = __builtin_amdgcn_mfma_f32_16x16x32_bf16(pa, v0, o0, 0, 0, 0);
            o1 = __builtin_amdgcn_mfma_f32_16x16x32_bf16(pa, v1, o1, 0, 0, 0);
        }
    }

    // epilogue: per-split normalized partial + (m,l)
    #pragma unroll
    for (int r = 0; r < 4; r++) {
        float invl = 1.f / runl[r];
        int q = q0 + quad * 4 + r;
        size_t base = ((size_t)(b * NPOS + q) * SPLIT + split) * 32;
        Opart[base + n16]      = (_Float16)(o0[r] * invl);
        Opart[base + 16 + n16] = (_Float16)(o1[r] * invl);
        if (n16 == 0)
            ml[(size_t)(b * NPOS + q) * SPLIT + split] = make_float2(runm[r], runl[r]);
    }
}

// ---------------------------------------------------------------------------
// Kernel 3: flash-combine the SPLIT partials + W-projection + residual.
// Grid (N/32, B), 256 threads, 32 queries per block.
// ---------------------------------------------------------------------------
__global__ __launch_bounds__(256) void nlb_combine_kernel(
    const _Float16* __restrict__ Opart, const float2* __restrict__ ml,
    const float* __restrict__ w_w, const float* __restrict__ x,
    float* __restrict__ out)
{
    __shared__ float wf[64][33];
    __shared__ float wts[32][17];
    __shared__ float of[32][33];

    const int b  = blockIdx.y;
    const int q0 = blockIdx.x * 32;
    const int t  = threadIdx.x;

    for (int idx = t; idx < 2048; idx += 256) wf[idx >> 5][idx & 31] = w_w[idx];

    if (t < 32) {   // per-query merge coefficients c_s = exp2(m_s-m*)*l_s / sum
        const float2* mlq = ml + (size_t)(b * NPOS + q0 + t) * SPLIT;
        float2 v[SPLIT];
        float m = -1e30f;
        #pragma unroll
        for (int s = 0; s < SPLIT; s++) { v[s] = mlq[s]; m = fmaxf(m, v[s].x); }
        float suml = 0.f;
        #pragma unroll
        for (int s = 0; s < SPLIT; s++) {
            float wgt = __builtin_amdgcn_exp2f(v[s].x - m) * v[s].y;
            wts[t][s] = wgt;
            suml += wgt;
        }
        float inv = 1.f / suml;
        #pragma unroll
        for (int s = 0; s < SPLIT; s++) wts[t][s] *= inv;
    }
    __syncthreads();

    {   // merge partial O: thread -> (query, 4 dims)
        const int q = t & 31, dg = t >> 5;
        const _Float16* op = Opart + (size_t)(b * NPOS + q0 + q) * SPLIT * 32 + dg * 4;
        float a0 = 0.f, a1 = 0.f, a2 = 0.f, a3 = 0.f;
        #pragma unroll
        for (int s = 0; s < SPLIT; s++) {
            h4 hv = *(const h4*)(op + (size_t)s * 32);
            float c = wts[q][s];
            a0 += c * (float)hv[0]; a1 += c * (float)hv[1];
            a2 += c * (float)hv[2]; a3 += c * (float)hv[3];
        }
        of[q][dg * 4]     = a0; of[q][dg * 4 + 1] = a1;
        of[q][dg * 4 + 2] = a2; of[q][dg * 4 + 3] = a3;
    }
    __syncthreads();

    {   // y = W o + x: thread -> (query, 8 channels)
        const int q = t & 31, cg = t >> 5;
        const float* xb = x   + (size_t)b * CH * NPOS + q0 + q;
        float*       ob = out + (size_t)b * CH * NPOS + q0 + q;
        #pragma unroll
        for (int cc = 0; cc < 8; cc++) {
            int ch = cg * 8 + cc;
            float acc = 0.f;
            #pragma unroll
            for (int i = 0; i < 32; i++) acc += wf[ch][i] * of[q][i];
            ob[(size_t)ch * NPOS] = acc + xb[(size_t)ch * NPOS];
        }
    }
}

extern "C" void kernel_launch(void* const* d_in, const int* in_sizes, int n_in,
                              void* d_out, int out_size, void* d_ws, size_t ws_size,
                              hipStream_t stream) {
    const float* x    = (const float*)d_in[0];
    const float* g_w  = (const float*)d_in[1];
    const float* th_w = (const float*)d_in[2];
    const float* ph_w = (const float*)d_in[3];
    const float* w_w  = (const float*)d_in[4];
    float* out = (float*)d_out;

    const size_t SZ = (size_t)BATCH * NPOS * INTER;   // 409600 elements
    short* Qhi = (short*)d_ws;
    short* Qlo = Qhi + SZ;
    short* Khi = Qlo + SZ;
    short* Klo = Khi + SZ;
    short* Vt  = Klo + SZ;
    _Float16* Opart = (_Float16*)(Vt + SZ);           // [B][N][SPLIT][32] fp16
    float2*   ml    = (float2*)(Opart + SZ * SPLIT);  // [B][N][SPLIT]

    nlb_proj_kernel<<<dim3(NPOS / 64, 3, BATCH), 256, 0, stream>>>(
        x, g_w, th_w, ph_w, Qhi, Qlo, Khi, Klo, Vt);
    nlb_flash_kernel<<<dim3(NPOS / 64, SPLIT, BATCH), 256, 0, stream>>>(
        Qhi, Qlo, Khi, Klo, Vt, Opart, ml);
    nlb_combine_kernel<<<dim3(NPOS / 32, BATCH), 256, 0, stream>>>(
        Opart, ml, w_w, x, out);
}

// Round 5
// 117.699 us; speedup vs baseline: 3.9127x; 1.1993x over previous
//
#include <hip/hip_runtime.h>
#include <math.h>

// Problem constants (B=2, C=64, inter=32, H=W=80 -> N=6400)
#define BATCH 2
#define CH    64
#define INTER 32
#define NPOS  6400
#define LOG2E 1.44269504088896f
#define SPLIT 10          // key-dim split factor
#define TPB   5           // 128-key tiles per split chunk (5*128*10 = 6400)

typedef _Float16 f16x8 __attribute__((ext_vector_type(8)));  // MFMA A/B frag
typedef _Float16 h4    __attribute__((ext_vector_type(4)));
typedef float    f32x4 __attribute__((ext_vector_type(4)));  // MFMA C/D

// ---------------------------------------------------------------------------
// Kernel 1: projections -> fp16 workspace. Grid (N/64, 3, B); blockIdx.y:
//   0: theta -> Qh [b][n][32], scaled by log2(e)
//   1: phi   -> Kh [b][n][32]
//   2: g     -> Vt [b][32][N] with per-128-tile KEY SWIZZLE: column
//      tile*128 + (key&15)*8 + (key>>4)  (matches flash P layout k~)
// x tile in VGPRs (coalesced), W rows wave-uniform (scalar loads);
// LDS only for the Q/K output transpose.
// ---------------------------------------------------------------------------
__global__ __launch_bounds__(256) void nlb_proj_kernel(
    const float* __restrict__ x,
    const float* __restrict__ g_w,
    const float* __restrict__ th_w,
    const float* __restrict__ ph_w,
    _Float16* __restrict__ Qh, _Float16* __restrict__ Kh,
    _Float16* __restrict__ Vt)
{
    const int b  = blockIdx.z;
    const int p  = blockIdx.y;
    const int n0 = blockIdx.x * 64;
    const int t  = threadIdx.x;
    const int w  = __builtin_amdgcn_readfirstlane(t) >> 6;  // wave id (uniform)
    const int lane = t & 63;

    const float* wsrc = (p == 0) ? th_w : (p == 1) ? ph_w : g_w;
    const float* xg = x + (size_t)b * CH * NPOS + n0 + lane;

    float xr[64];
    #pragma unroll
    for (int c = 0; c < 64; c++) xr[c] = xg[(size_t)c * NPOS];

    __shared__ float buf[32][65];

    float accs[8];
    #pragma unroll
    for (int rr = 0; rr < 8; rr++) {
        const int row = w * 8 + rr;                  // wave-uniform
        const float* wr = wsrc + row * 64;           // -> scalar loads
        float a0 = 0.f, a1 = 0.f, a2 = 0.f, a3 = 0.f;
        #pragma unroll
        for (int c = 0; c < 16; c++) {
            a0 += wr[c]      * xr[c];
            a1 += wr[c + 16] * xr[c + 16];
            a2 += wr[c + 32] * xr[c + 32];
            a3 += wr[c + 48] * xr[c + 48];
        }
        accs[rr] = (a0 + a1) + (a2 + a3);
    }

    if (p == 2) {   // V^T with key swizzle inside each 128-key tile
        const int n    = n0 + lane;
        const int kk   = n & 127;
        const int ksw  = (kk & 15) * 8 + (kk >> 4);
        const size_t col = (size_t)(n >> 7) * 128 + ksw;
        #pragma unroll
        for (int rr = 0; rr < 8; rr++)
            Vt[((size_t)b * 32 + w * 8 + rr) * NPOS + col] = (_Float16)accs[rr];
        return;
    }

    #pragma unroll
    for (int rr = 0; rr < 8; rr++) buf[w * 8 + rr][lane] = accs[rr];
    __syncthreads();

    const float scale = (p == 0) ? LOG2E : 1.f;
    _Float16* dst = (p == 0) ? Qh : Kh;
    const int pos = t >> 2, ic = t & 3;   // 8 consecutive inter-ch per thread
    f16x8 hv;
    #pragma unroll
    for (int j = 0; j < 8; j++)
        hv[j] = (_Float16)(buf[ic * 8 + j][pos] * scale);
    *(f16x8*)(dst + ((size_t)b * NPOS + n0 + pos) * 32 + ic * 8) = hv;
}

// ---------------------------------------------------------------------------
// Kernel 2: fp16 MFMA flash attention, split-K. Grid (N/64, SPLIT, B),
// 256 thr = 4 waves x 16 queries, 128-key tiles.
// Layouts: C/D col=lane&15,row=quad*4+reg; A[m=lane&15][k=quad*8+j];
//          B[k=quad*8+j][n=lane&15].
// P stored per wave as [q][k~] with k~=(key&15)*8+(key>>4): each lane's 8
// exp-scores per row are contiguous -> ONE ds_write_b128 per row (was 32xb16).
// V arrives pre-swizzled in the same k~ order (proj kernel), so PV A- and
// B-frag reads are both contiguous b128.
// ---------------------------------------------------------------------------
__global__ __launch_bounds__(256) void nlb_flash_kernel(
    const _Float16* __restrict__ Qh, const _Float16* __restrict__ Kh,
    const _Float16* __restrict__ Vt,
    _Float16* __restrict__ Opart, float2* __restrict__ ml)
{
    __shared__ __align__(16) _Float16 ks[128][40];    // 80B rows
    __shared__ __align__(16) _Float16 vs[32][144];    // 288B rows (swizzled k~)
    __shared__ __align__(16) _Float16 pm[4][16][136]; // per-wave P [q][k~]

    const int b     = blockIdx.z;
    const int split = blockIdx.y;
    const int t     = threadIdx.x;
    const int w     = t >> 6;
    const int lane  = t & 63;
    const int n16   = lane & 15;
    const int quad  = lane >> 4;
    const int q0    = blockIdx.x * 64 + w * 16;

    const f16x8 qa = *(const f16x8*)(Qh + ((size_t)b * NPOS + q0 + n16) * 32 + quad * 8);

    f32x4 o0 = {0.f, 0.f, 0.f, 0.f};
    f32x4 o1 = {0.f, 0.f, 0.f, 0.f};
    float runm[4] = {-1e30f, -1e30f, -1e30f, -1e30f};
    float lloc[4] = {0.f, 0.f, 0.f, 0.f};   // lane-local l partials

    const _Float16* KB = Kh + (size_t)b * NPOS * 32;
    const _Float16* VB = Vt + (size_t)b * 32 * NPOS;

    const int kt0 = split * TPB;
    for (int kt = kt0; kt < kt0 + TPB; kt++) {
        __syncthreads();   // previous tile's LDS reads complete
        {
            const int k0 = kt * 128;
            #pragma unroll
            for (int i = 0; i < 2; i++) {
                int c = t + i * 256;
                int key = c >> 2, part = c & 3;
                *(f16x8*)&ks[key][part * 8] =
                    *(const f16x8*)(KB + (size_t)(k0 + key) * 32 + part * 8);
                int dim = c >> 4, kp = c & 15;
                *(f16x8*)&vs[dim][kp * 8] =
                    *(const f16x8*)(VB + (size_t)dim * NPOS + k0 + kp * 8);
            }
        }
        __syncthreads();

        // S = Q K^T (one fp16 MFMA per 16-key group), log2-domain
        f32x4 sc[8];
        #pragma unroll
        for (int g = 0; g < 8; g++) {
            f16x8 kf = *(const f16x8*)&ks[g * 16 + n16][quad * 8];
            f32x4 z = {0.f, 0.f, 0.f, 0.f};
            sc[g] = __builtin_amdgcn_mfma_f32_16x16x32_f16(qa, kf, z, 0, 0, 0);
        }

        // online softmax; P row packed to one b128 LDS write
        #pragma unroll
        for (int r = 0; r < 4; r++) {
            float m = sc[0][r];
            #pragma unroll
            for (int g = 1; g < 8; g++) m = fmaxf(m, sc[g][r]);
            m = fmaxf(m, __shfl_xor(m, 1));
            m = fmaxf(m, __shfl_xor(m, 2));
            m = fmaxf(m, __shfl_xor(m, 4));
            m = fmaxf(m, __shfl_xor(m, 8));
            float nm = fmaxf(runm[r], m);
            float a  = __builtin_amdgcn_exp2f(runm[r] - nm);
            float ls = 0.f;
            f16x8 pv;
            #pragma unroll
            for (int g = 0; g < 8; g++) {
                float p = __builtin_amdgcn_exp2f(sc[g][r] - nm);
                pv[g] = (_Float16)p;
                ls += p;
            }
            lloc[r] = lloc[r] * a + ls;   // cross-lane sum deferred to end
            runm[r] = nm;
            o0[r] *= a; o1[r] *= a;
            // lane's 8 keys for this row are k~ = n16*8 + g : contiguous
            *(f16x8*)&pm[w][quad * 4 + r][n16 * 8] = pv;
        }

        // O += P V  (same-wave LDS write->read, in-order DS pipe)
        #pragma unroll
        for (int kc = 0; kc < 4; kc++) {
            f16x8 pa = *(const f16x8*)&pm[w][n16][kc * 32 + quad * 8];
            f16x8 v0 = *(const f16x8*)&vs[n16][kc * 32 + quad * 8];
            f16x8 v1 = *(const f16x8*)&vs[16 + n16][kc * 32 + quad * 8];
            o0 = __builtin_amdgcn_mfma_f32_16x16x32_f16(pa, v0, o0, 0, 0, 0);
            o1 = __builtin_amdgcn_mfma_f32_16x16x32_f16(pa, v1, o1, 0, 0, 0);
        }
    }

    // epilogue: cross-lane l reduce, normalized partial + (m,l)
    #pragma unroll
    for (int r = 0; r < 4; r++) {
        float l = lloc[r];
        l += __shfl_xor(l, 1); l += __shfl_xor(l, 2);
        l += __shfl_xor(l, 4); l += __shfl_xor(l, 8);
        float invl = 1.f / l;
        int q = q0 + quad * 4 + r;
        size_t base = ((size_t)(b * SPLIT + split) * NPOS + q) * 32;
        Opart[base + n16]      = (_Float16)(o0[r] * invl);
        Opart[base + 16 + n16] = (_Float16)(o1[r] * invl);
        if (n16 == 0)
            ml[(size_t)(b * SPLIT + split) * NPOS + q] = make_float2(runm[r], l);
    }
}

// ---------------------------------------------------------------------------
// Kernel 3: flash-combine the SPLIT partials + W-projection + residual.
// Grid (N/32, B). Opart layout [b][split][q][32] -> coalesced 8B reads.
// ---------------------------------------------------------------------------
__global__ __launch_bounds__(256) void nlb_combine_kernel(
    const _Float16* __restrict__ Opart, const float2* __restrict__ ml,
    const float* __restrict__ w_w, const float* __restrict__ x,
    float* __restrict__ out)
{
    __shared__ float wf[64][33];
    __shared__ float wts[32][12];
    __shared__ float of[32][33];

    const int b  = blockIdx.y;
    const int q0 = blockIdx.x * 32;
    const int t  = threadIdx.x;

    for (int idx = t; idx < 2048; idx += 256) wf[idx >> 5][idx & 31] = w_w[idx];

    if (t < 32) {   // merge coefficients c_s = exp2(m_s-m*)*l_s / sum
        float2 v[SPLIT];
        float m = -1e30f;
        #pragma unroll
        for (int s = 0; s < SPLIT; s++) {
            v[s] = ml[(size_t)(b * SPLIT + s) * NPOS + q0 + t];
            m = fmaxf(m, v[s].x);
        }
        float suml = 0.f;
        #pragma unroll
        for (int s = 0; s < SPLIT; s++) {
            float wgt = __builtin_amdgcn_exp2f(v[s].x - m) * v[s].y;
            wts[t][s] = wgt;
            suml += wgt;
        }
        float inv = 1.f / suml;
        #pragma unroll
        for (int s = 0; s < SPLIT; s++) wts[t][s] *= inv;
    }
    __syncthreads();

    {   // merge partial O: thread -> (q = t>>3, dims dg*4..dg*4+3) COALESCED
        const int q = t >> 3, dg = t & 7;
        float a0 = 0.f, a1 = 0.f, a2 = 0.f, a3 = 0.f;
        #pragma unroll
        for (int s = 0; s < SPLIT; s++) {
            h4 hv = *(const h4*)(Opart +
                ((size_t)(b * SPLIT + s) * NPOS + q0 + q) * 32 + dg * 4);
            float c = wts[q][s];
            a0 += c * (float)hv[0]; a1 += c * (float)hv[1];
            a2 += c * (float)hv[2]; a3 += c * (float)hv[3];
        }
        of[q][dg * 4]     = a0; of[q][dg * 4 + 1] = a1;
        of[q][dg * 4 + 2] = a2; of[q][dg * 4 + 3] = a3;
    }
    __syncthreads();

    {   // y = W o + x: thread -> (query, 8 channels)
        const int q = t & 31, cg = t >> 5;
        const float* xb = x   + (size_t)b * CH * NPOS + q0 + q;
        float*       ob = out + (size_t)b * CH * NPOS + q0 + q;
        #pragma unroll
        for (int cc = 0; cc < 8; cc++) {
            int ch = cg * 8 + cc;
            float acc = 0.f;
            #pragma unroll
            for (int i = 0; i < 32; i++) acc += wf[ch][i] * of[q][i];
            ob[(size_t)ch * NPOS] = acc + xb[(size_t)ch * NPOS];
        }
    }
}

extern "C" void kernel_launch(void* const* d_in, const int* in_sizes, int n_in,
                              void* d_out, int out_size, void* d_ws, size_t ws_size,
                              hipStream_t stream) {
    const float* x    = (const float*)d_in[0];
    const float* g_w  = (const float*)d_in[1];
    const float* th_w = (const float*)d_in[2];
    const float* ph_w = (const float*)d_in[3];
    const float* w_w  = (const float*)d_in[4];
    float* out = (float*)d_out;

    const size_t SZ = (size_t)BATCH * NPOS * INTER;   // 409600 elements
    _Float16* Qh = (_Float16*)d_ws;
    _Float16* Kh = Qh + SZ;
    _Float16* Vt = Kh + SZ;
    _Float16* Opart = Vt + SZ;                         // [B][SPLIT][N][32]
    float2*   ml    = (float2*)(Opart + SZ * SPLIT);   // [B][SPLIT][N]

    nlb_proj_kernel<<<dim3(NPOS / 64, 3, BATCH), 256, 0, stream>>>(
        x, g_w, th_w, ph_w, Qh, Kh, Vt);
    nlb_flash_kernel<<<dim3(NPOS / 64, SPLIT, BATCH), 256, 0, stream>>>(
        Qh, Kh, Vt, Opart, ml);
    nlb_combine_kernel<<<dim3(NPOS / 32, BATCH), 256, 0, stream>>>(
        Opart, ml, w_w, x, out);
}

// Round 6
// 112.075 us; speedup vs baseline: 4.1090x; 1.0502x over previous
//
#include <hip/hip_runtime.h>
#include <math.h>

// Problem constants (B=2, C=64, inter=32, H=W=80 -> N=6400)
#define BATCH 2
#define CH    64
#define INTER 32
#define NPOS  6400
#define LOG2E 1.44269504088896f
#define SPLIT 10          // key-dim split factor
#define TPB   5           // 128-key tiles per split chunk (5*128*10 = 6400)

typedef _Float16 f16x8 __attribute__((ext_vector_type(8)));  // MFMA A/B frag
typedef _Float16 h4    __attribute__((ext_vector_type(4)));
typedef float    f32x4 __attribute__((ext_vector_type(4)));  // MFMA C/D

// max-reduce over a 16-lane DPP row (VALU pipe, no DS ops).
// row_ror:N ctrl = 0x120 | N ; after ror 1,2,4,8 every lane holds row max.
template <int N>
static __device__ __forceinline__ float max_ror(float x) {
    int r = __builtin_amdgcn_mov_dpp(__builtin_bit_cast(int, x),
                                     0x120 | N, 0xF, 0xF, true);
    return fmaxf(x, __builtin_bit_cast(float, r));
}
static __device__ __forceinline__ float rowmax16(float x) {
    x = max_ror<1>(x); x = max_ror<2>(x);
    x = max_ror<4>(x); x = max_ror<8>(x);
    return x;
}

// ---------------------------------------------------------------------------
// Kernel 1: projections -> fp16 workspace. Grid (N/64, 3, B); blockIdx.y:
//   0: theta -> Qh [b][n][32], scaled by log2(e)
//   1: phi   -> Kh [b][n][32]
//   2: g     -> Vt [b][32][N] with per-128-tile KEY SWIZZLE: column
//      tile*128 + (key&15)*8 + (key>>4)  (matches flash P layout k~)
// ---------------------------------------------------------------------------
__global__ __launch_bounds__(256) void nlb_proj_kernel(
    const float* __restrict__ x,
    const float* __restrict__ g_w,
    const float* __restrict__ th_w,
    const float* __restrict__ ph_w,
    _Float16* __restrict__ Qh, _Float16* __restrict__ Kh,
    _Float16* __restrict__ Vt)
{
    const int b  = blockIdx.z;
    const int p  = blockIdx.y;
    const int n0 = blockIdx.x * 64;
    const int t  = threadIdx.x;
    const int w  = __builtin_amdgcn_readfirstlane(t) >> 6;  // wave id (uniform)
    const int lane = t & 63;

    const float* wsrc = (p == 0) ? th_w : (p == 1) ? ph_w : g_w;
    const float* xg = x + (size_t)b * CH * NPOS + n0 + lane;

    float xr[64];
    #pragma unroll
    for (int c = 0; c < 64; c++) xr[c] = xg[(size_t)c * NPOS];

    __shared__ float buf[32][65];

    float accs[8];
    #pragma unroll
    for (int rr = 0; rr < 8; rr++) {
        const int row = w * 8 + rr;                  // wave-uniform
        const float* wr = wsrc + row * 64;           // -> scalar loads
        float a0 = 0.f, a1 = 0.f, a2 = 0.f, a3 = 0.f;
        #pragma unroll
        for (int c = 0; c < 16; c++) {
            a0 += wr[c]      * xr[c];
            a1 += wr[c + 16] * xr[c + 16];
            a2 += wr[c + 32] * xr[c + 32];
            a3 += wr[c + 48] * xr[c + 48];
        }
        accs[rr] = (a0 + a1) + (a2 + a3);
    }

    if (p == 2) {   // V^T with key swizzle inside each 128-key tile
        const int n    = n0 + lane;
        const int kk   = n & 127;
        const int ksw  = (kk & 15) * 8 + (kk >> 4);
        const size_t col = (size_t)(n >> 7) * 128 + ksw;
        #pragma unroll
        for (int rr = 0; rr < 8; rr++)
            Vt[((size_t)b * 32 + w * 8 + rr) * NPOS + col] = (_Float16)accs[rr];
        return;
    }

    #pragma unroll
    for (int rr = 0; rr < 8; rr++) buf[w * 8 + rr][lane] = accs[rr];
    __syncthreads();

    const float scale = (p == 0) ? LOG2E : 1.f;
    _Float16* dst = (p == 0) ? Qh : Kh;
    const int pos = t >> 2, ic = t & 3;   // 8 consecutive inter-ch per thread
    f16x8 hv;
    #pragma unroll
    for (int j = 0; j < 8; j++)
        hv[j] = (_Float16)(buf[ic * 8 + j][pos] * scale);
    *(f16x8*)(dst + ((size_t)b * NPOS + n0 + pos) * 32 + ic * 8) = hv;
}

// ---------------------------------------------------------------------------
// Kernel 2: fp16 MFMA flash attention, split-K, VGPR-prefetch pipeline.
// Grid (N/64, SPLIT, B), 256 thr = 4 waves x 16 queries, 128-key tiles.
// Layouts: C/D col=lane&15,row=quad*4+reg; A[m=lane&15][k=quad*8+j];
//          B[k=quad*8+j][n=lane&15]. P/V use swizzled key order
//          k~=(key&15)*8+(key>>4) so P rows pack to one b128 write.
// Pipeline per tile: barrier -> VGPR->LDS -> barrier -> issue next-tile
// global loads (stay in flight) -> compute.
// ---------------------------------------------------------------------------
__global__ __launch_bounds__(256) void nlb_flash_kernel(
    const _Float16* __restrict__ Qh, const _Float16* __restrict__ Kh,
    const _Float16* __restrict__ Vt,
    _Float16* __restrict__ Opart, float2* __restrict__ ml)
{
    __shared__ __align__(16) _Float16 ks[128][40];    // 80B rows
    __shared__ __align__(16) _Float16 vs[32][144];    // 288B rows (swizzled k~)
    __shared__ __align__(16) _Float16 pm[4][16][136]; // per-wave P [q][k~]

    const int b     = blockIdx.z;
    const int split = blockIdx.y;
    const int t     = threadIdx.x;
    const int w     = t >> 6;
    const int lane  = t & 63;
    const int n16   = lane & 15;
    const int quad  = lane >> 4;
    const int q0    = blockIdx.x * 64 + w * 16;

    const f16x8 qa = *(const f16x8*)(Qh + ((size_t)b * NPOS + q0 + n16) * 32 + quad * 8);

    f32x4 o0 = {0.f, 0.f, 0.f, 0.f};
    f32x4 o1 = {0.f, 0.f, 0.f, 0.f};
    float runm[4] = {-1e30f, -1e30f, -1e30f, -1e30f};
    float lloc[4] = {0.f, 0.f, 0.f, 0.f};   // lane-local l partials

    const _Float16* KB = Kh + (size_t)b * NPOS * 32;
    const _Float16* VB = Vt + (size_t)b * 32 * NPOS;

    // staging address components (two 16B chunks per thread for K and V)
    const int key0 = t >> 2,            part0 = t & 3;
    const int key1 = (t + 256) >> 2,    part1 = t & 3;          // +256 keeps part
    const int dim0 = t >> 4,            kp0   = t & 15;
    const int dim1 = (t + 256) >> 4,    kp1   = t & 15;

    f16x8 kr0, kr1, vr0, vr1;
    const int kt0 = split * TPB;
    {   // prologue fetch of first tile
        const int k0 = kt0 * 128;
        kr0 = *(const f16x8*)(KB + (size_t)(k0 + key0) * 32 + part0 * 8);
        kr1 = *(const f16x8*)(KB + (size_t)(k0 + key1) * 32 + part1 * 8);
        vr0 = *(const f16x8*)(VB + (size_t)dim0 * NPOS + k0 + kp0 * 8);
        vr1 = *(const f16x8*)(VB + (size_t)dim1 * NPOS + k0 + kp1 * 8);
    }

    for (int kt = kt0; kt < kt0 + TPB; kt++) {
        __syncthreads();   // previous tile's LDS reads complete
        *(f16x8*)&ks[key0][part0 * 8] = kr0;
        *(f16x8*)&ks[key1][part1 * 8] = kr1;
        *(f16x8*)&vs[dim0][kp0 * 8]   = vr0;
        *(f16x8*)&vs[dim1][kp1 * 8]   = vr1;
        __syncthreads();

        {   // issue next-tile global loads; they stay in flight during compute
            const int ktn = (kt + 1 < kt0 + TPB) ? kt + 1 : kt;
            const int k0n = ktn * 128;
            kr0 = *(const f16x8*)(KB + (size_t)(k0n + key0) * 32 + part0 * 8);
            kr1 = *(const f16x8*)(KB + (size_t)(k0n + key1) * 32 + part1 * 8);
            vr0 = *(const f16x8*)(VB + (size_t)dim0 * NPOS + k0n + kp0 * 8);
            vr1 = *(const f16x8*)(VB + (size_t)dim1 * NPOS + k0n + kp1 * 8);
        }

        // S = Q K^T (one fp16 MFMA per 16-key group), log2-domain
        f32x4 sc[8];
        #pragma unroll
        for (int g = 0; g < 8; g++) {
            f16x8 kf = *(const f16x8*)&ks[g * 16 + n16][quad * 8];
            f32x4 z = {0.f, 0.f, 0.f, 0.f};
            sc[g] = __builtin_amdgcn_mfma_f32_16x16x32_f16(qa, kf, z, 0, 0, 0);
        }

        // online softmax; max-reduce on VALU (DPP), P packs to one b128 write
        #pragma unroll
        for (int r = 0; r < 4; r++) {
            float m01 = fmaxf(sc[0][r], sc[1][r]);
            float m23 = fmaxf(sc[2][r], sc[3][r]);
            float m45 = fmaxf(sc[4][r], sc[5][r]);
            float m67 = fmaxf(sc[6][r], sc[7][r]);
            float m = fmaxf(fmaxf(m01, m23), fmaxf(m45, m67));
            m = rowmax16(m);
            float nm = fmaxf(runm[r], m);
            float a  = __builtin_amdgcn_exp2f(runm[r] - nm);
            float ls = 0.f;
            f16x8 pv;
            #pragma unroll
            for (int g = 0; g < 8; g++) {
                float p = __builtin_amdgcn_exp2f(sc[g][r] - nm);
                pv[g] = (_Float16)p;
                ls += p;
            }
            lloc[r] = lloc[r] * a + ls;   // cross-lane sum deferred to end
            runm[r] = nm;
            o0[r] *= a; o1[r] *= a;
            // lane's 8 keys for this row are k~ = n16*8 + g : contiguous
            *(f16x8*)&pm[w][quad * 4 + r][n16 * 8] = pv;
        }

        // O += P V  (same-wave LDS write->read, in-order DS pipe)
        #pragma unroll
        for (int kc = 0; kc < 4; kc++) {
            f16x8 pa = *(const f16x8*)&pm[w][n16][kc * 32 + quad * 8];
            f16x8 v0 = *(const f16x8*)&vs[n16][kc * 32 + quad * 8];
            f16x8 v1 = *(const f16x8*)&vs[16 + n16][kc * 32 + quad * 8];
            o0 = __builtin_amdgcn_mfma_f32_16x16x32_f16(pa, v0, o0, 0, 0, 0);
            o1 = __builtin_amdgcn_mfma_f32_16x16x32_f16(pa, v1, o1, 0, 0, 0);
        }
    }

    // epilogue: cross-lane l reduce, normalized partial + (m,l)
    #pragma unroll
    for (int r = 0; r < 4; r++) {
        float l = lloc[r];
        l += __shfl_xor(l, 1); l += __shfl_xor(l, 2);
        l += __shfl_xor(l, 4); l += __shfl_xor(l, 8);
        float invl = 1.f / l;
        int q = q0 + quad * 4 + r;
        size_t base = ((size_t)(b * SPLIT + split) * NPOS + q) * 32;
        Opart[base + n16]      = (_Float16)(o0[r] * invl);
        Opart[base + 16 + n16] = (_Float16)(o1[r] * invl);
        if (n16 == 0)
            ml[(size_t)(b * SPLIT + split) * NPOS + q] = make_float2(runm[r], l);
    }
}

// ---------------------------------------------------------------------------
// Kernel 3: flash-combine the SPLIT partials + W-projection + residual.
// Grid (N/32, B). Opart layout [b][split][q][32] -> coalesced 8B reads.
// ---------------------------------------------------------------------------
__global__ __launch_bounds__(256) void nlb_combine_kernel(
    const _Float16* __restrict__ Opart, const float2* __restrict__ ml,
    const float* __restrict__ w_w, const float* __restrict__ x,
    float* __restrict__ out)
{
    __shared__ float wf[64][33];
    __shared__ float wts[32][12];
    __shared__ float of[32][33];

    const int b  = blockIdx.y;
    const int q0 = blockIdx.x * 32;
    const int t  = threadIdx.x;

    for (int idx = t; idx < 2048; idx += 256) wf[idx >> 5][idx & 31] = w_w[idx];

    if (t < 32) {   // merge coefficients c_s = exp2(m_s-m*)*l_s / sum
        float2 v[SPLIT];
        float m = -1e30f;
        #pragma unroll
        for (int s = 0; s < SPLIT; s++) {
            v[s] = ml[(size_t)(b * SPLIT + s) * NPOS + q0 + t];
            m = fmaxf(m, v[s].x);
        }
        float suml = 0.f;
        #pragma unroll
        for (int s = 0; s < SPLIT; s++) {
            float wgt = __builtin_amdgcn_exp2f(v[s].x - m) * v[s].y;
            wts[t][s] = wgt;
            suml += wgt;
        }
        float inv = 1.f / suml;
        #pragma unroll
        for (int s = 0; s < SPLIT; s++) wts[t][s] *= inv;
    }
    __syncthreads();

    {   // merge partial O: thread -> (q = t>>3, dims dg*4..dg*4+3) COALESCED
        const int q = t >> 3, dg = t & 7;
        float a0 = 0.f, a1 = 0.f, a2 = 0.f, a3 = 0.f;
        #pragma unroll
        for (int s = 0; s < SPLIT; s++) {
            h4 hv = *(const h4*)(Opart +
                ((size_t)(b * SPLIT + s) * NPOS + q0 + q) * 32 + dg * 4);
            float c = wts[q][s];
            a0 += c * (float)hv[0]; a1 += c * (float)hv[1];
            a2 += c * (float)hv[2]; a3 += c * (float)hv[3];
        }
        of[q][dg * 4]     = a0; of[q][dg * 4 + 1] = a1;
        of[q][dg * 4 + 2] = a2; of[q][dg * 4 + 3] = a3;
    }
    __syncthreads();

    {   // y = W o + x: thread -> (query, 8 channels)
        const int q = t & 31, cg = t >> 5;
        const float* xb = x   + (size_t)b * CH * NPOS + q0 + q;
        float*       ob = out + (size_t)b * CH * NPOS + q0 + q;
        #pragma unroll
        for (int cc = 0; cc < 8; cc++) {
            int ch = cg * 8 + cc;
            float acc = 0.f;
            #pragma unroll
            for (int i = 0; i < 32; i++) acc += wf[ch][i] * of[q][i];
            ob[(size_t)ch * NPOS] = acc + xb[(size_t)ch * NPOS];
        }
    }
}

extern "C" void kernel_launch(void* const* d_in, const int* in_sizes, int n_in,
                              void* d_out, int out_size, void* d_ws, size_t ws_size,
                              hipStream_t stream) {
    const float* x    = (const float*)d_in[0];
    const float* g_w  = (const float*)d_in[1];
    const float* th_w = (const float*)d_in[2];
    const float* ph_w = (const float*)d_in[3];
    const float* w_w  = (const float*)d_in[4];
    float* out = (float*)d_out;

    const size_t SZ = (size_t)BATCH * NPOS * INTER;   // 409600 elements
    _Float16* Qh = (_Float16*)d_ws;
    _Float16* Kh = Qh + SZ;
    _Float16* Vt = Kh + SZ;
    _Float16* Opart = Vt + SZ;                         // [B][SPLIT][N][32]
    float2*   ml    = (float2*)(Opart + SZ * SPLIT);   // [B][SPLIT][N]

    nlb_proj_kernel<<<dim3(NPOS / 64, 3, BATCH), 256, 0, stream>>>(
        x, g_w, th_w, ph_w, Qh, Kh, Vt);
    nlb_flash_kernel<<<dim3(NPOS / 64, SPLIT, BATCH), 256, 0, stream>>>(
        Qh, Kh, Vt, Opart, ml);
    nlb_combine_kernel<<<dim3(NPOS / 32, BATCH), 256, 0, stream>>>(
        Opart, ml, w_w, x, out);
}